// Round 14
// baseline (4920.668 us; speedup 1.0000x reference)
//
#include <hip/hip_runtime.h>
#include <hip/hip_bf16.h>
#include <stdint.h>

// ---------------- problem dims ----------------
#define BB   64
#define TT   511
#define SS   512
#define DD   500
#define KXP  512          // padded input dim for layer-0 input GEMM
#define HG   384
#define G4   1536
#define HE   64
#define E4   256
#define NSEQ (BB*SS)      // 32768
#define POISON32 0x7FC07FC0u

typedef __hip_bfloat16 bf16;
typedef float  floatx4 __attribute__((ext_vector_type(4)));
typedef int    intx4   __attribute__((ext_vector_type(4)));
typedef __bf16 bfrag8  __attribute__((ext_vector_type(8)));
typedef unsigned short ushort8 __attribute__((ext_vector_type(8)));

// v_mfma_f32_16x16x32_bf16 fragment layout (gfx950):
//   A: lane l holds A[l&15][8*(l>>4)+i]      (16B contiguous along K, A stored [M][K])
//   B: lane l holds W[n=l&15][8*(l>>4)+i]    (weights stored [N][K] = torch [out][in])
//   D: lane l, reg r holds D[4*(l>>4)+r][l&15]
static __device__ __forceinline__ floatx4 MFMA16(bfrag8 a, bfrag8 b, floatx4 c){
  return __builtin_amdgcn_mfma_f32_16x16x32_bf16(a, b, c, 0, 0, 0);
}
static __device__ __forceinline__ float sigm_(float x){ return 1.f/(1.f + __expf(-x)); }
static __device__ __forceinline__ float tanh_(float x){
  x = fminf(fmaxf(x, -15.f), 15.f);
  float e = __expf(2.f*x);
  return (e - 1.f)/(e + 1.f);
}
// per-lane gate activation: sigm for i,f,o; tanh via 2*sigm(2x)-1 for g
static __device__ __forceinline__ float actv(float x, bool isg){
  float s = 1.f/(1.f + __expf(isg ? -2.f*x : -x));
  return isg ? (2.f*s - 1.f) : s;
}
static __device__ __forceinline__ float b2f(unsigned short u){
  union { unsigned int i; float f; } x; x.i = ((unsigned int)u)<<16; return x.f;
}
static __device__ __forceinline__ unsigned short f2bu(float f){
  bf16 b = __float2bfloat16(f);
  return *reinterpret_cast<unsigned short*>(&b);
}
static __device__ __forceinline__ bfrag8 asfrag(intx4 v){
  union { intx4 i; bfrag8 f; } u; u.i = v; return u.f;
}

// ---- coherence-point accesses for cross-block RNN state (HIP atomics) ----
static __device__ __forceinline__ intx4 ld16_chk(const bf16* p){
  unsigned long long u0 = __hip_atomic_load((const unsigned long long*)p,     __ATOMIC_RELAXED, __HIP_MEMORY_SCOPE_SYSTEM);
  unsigned long long u1 = __hip_atomic_load((const unsigned long long*)p + 1, __ATOMIC_RELAXED, __HIP_MEMORY_SCOPE_SYSTEM);
  union { unsigned long long u[2]; intx4 v; } x; x.u[0]=u0; x.u[1]=u1;
  return x.v;
}
static __device__ __forceinline__ bool okfrag(intx4 v){
  return (((unsigned)v.x) != POISON32) & (((unsigned)v.y) != POISON32) &
         (((unsigned)v.z) != POISON32) & (((unsigned)v.w) != POISON32);
}
static __device__ __forceinline__ void stpair_coh(bf16* p, float lo, float hi){
  unsigned int pk = (unsigned int)f2bu(lo) | ((unsigned int)f2bu(hi) << 16);
  __hip_atomic_store((unsigned int*)p, pk, __ATOMIC_RELAXED, __HIP_MEMORY_SCOPE_SYSTEM);
}
// validated loads: first pass pipelined; retry ONLY invalid frags (rare —
// flag wait already placed us within the producer's store-completion window)
template<int NF>
static __device__ __forceinline__ void loadN_chk(const bf16* base, int lq, intx4* ha){
  #pragma unroll
  for (int kf=0;kf<NF;++kf) ha[kf] = ld16_chk(base + kf*32 + lq*8);
  unsigned okm = 0;
  #pragma unroll
  for (int kf=0;kf<NF;++kf) if (okfrag(ha[kf])) okm |= (1u<<kf);
  const unsigned FULL = (1u<<NF)-1u;
  while (!__all(okm == FULL)){
    __builtin_amdgcn_s_sleep(1);
    #pragma unroll
    for (int kf=0;kf<NF;++kf){
      if (!(okm & (1u<<kf))){
        ha[kf] = ld16_chk(base + kf*32 + lq*8);
        if (okfrag(ha[kf])) okm |= (1u<<kf);
      }
    }
  }
}
static __device__ __forceinline__ void load24_chk(const bf16* b0, const bf16* b1, int lq, intx4* ha){
  #pragma unroll
  for (int kf=0;kf<24;++kf){
    const bf16* p = (kf<12) ? (b0 + kf*32 + lq*8) : (b1 + (kf-12)*32 + lq*8);
    ha[kf] = ld16_chk(p);
  }
  unsigned okm = 0;
  #pragma unroll
  for (int kf=0;kf<24;++kf) if (okfrag(ha[kf])) okm |= (1u<<kf);
  while (!__all(okm == 0xFFFFFFu)){
    __builtin_amdgcn_s_sleep(1);
    #pragma unroll
    for (int kf=0;kf<24;++kf){
      if (!(okm & (1u<<kf))){
        const bf16* p = (kf<12) ? (b0 + kf*32 + lq*8) : (b1 + (kf-12)*32 + lq*8);
        ha[kf] = ld16_chk(p);
        if (okfrag(ha[kf])) okm |= (1u<<kf);
      }
    }
  }
}

// ---------------------------------------------------------------------------
// prep: build padded bf16 X = [sentinel ; concat(input, tag)]  -> [32768][512]
// ---------------------------------------------------------------------------
__global__ __launch_bounds__(256) void prep_x(const float* __restrict__ input,
    const float* __restrict__ tag, const float* __restrict__ sent,
    bf16* __restrict__ Xb)
{
  const size_t N8 = (size_t)NSEQ*KXP/8;
  const size_t stp = (size_t)gridDim.x * blockDim.x;
  for (size_t i8 = (size_t)blockIdx.x*blockDim.x + threadIdx.x; i8 < N8; i8 += stp){
    int m = (int)(i8 >> 6);
    int k = ((int)i8 & 63) * 8;
    int b = m >> 9, s = m & 511;
    float v[8];
    if (s == 0){
      #pragma unroll
      for (int j=0;j<8;++j) v[j] = (k+j < DD) ? sent[k+j] : 0.f;
    } else if (k < 400){
      const float* src = input + (size_t)(b*TT + s-1)*400 + k;
      float4 a = *(const float4*)src;
      float4 c = *(const float4*)(src+4);
      v[0]=a.x; v[1]=a.y; v[2]=a.z; v[3]=a.w; v[4]=c.x; v[5]=c.y; v[6]=c.z; v[7]=c.w;
    } else if (k < 496){
      const float* src = tag + (size_t)(b*TT + s-1)*100 + (k-400);
      float4 a = *(const float4*)src;
      float4 c = *(const float4*)(src+4);
      v[0]=a.x; v[1]=a.y; v[2]=a.z; v[3]=a.w; v[4]=c.x; v[5]=c.y; v[6]=c.z; v[7]=c.w;
    } else if (k == 496){
      const float* src = tag + (size_t)(b*TT + s-1)*100 + 96;
      float4 a = *(const float4*)src;
      v[0]=a.x; v[1]=a.y; v[2]=a.z; v[3]=a.w; v[4]=0.f; v[5]=0.f; v[6]=0.f; v[7]=0.f;
    } else {
      #pragma unroll
      for (int j=0;j<8;++j) v[j]=0.f;
    }
    ushort8 o;
    #pragma unroll
    for (int j=0;j<8;++j) o[j] = f2bu(v[j]);
    *(ushort8*)&Xb[i8*8] = o;
  }
}

// ---------------------------------------------------------------------------
// prep: weight conversions with gate interleave n=4j+g, bias folds (4-wide),
// + POISON fill of write-once h buffers
// ---------------------------------------------------------------------------
__global__ __launch_bounds__(256) void prep_w(
  const float* __restrict__ gWih0, const float* __restrict__ gWhh0,
  const float* __restrict__ gbih0, const float* __restrict__ gbhh0,
  const float* __restrict__ gWih1, const float* __restrict__ gWhh1,
  const float* __restrict__ gbih1, const float* __restrict__ gbhh1,
  const float* __restrict__ eWih0, const float* __restrict__ eWhh0,
  const float* __restrict__ ebih0, const float* __restrict__ ebhh0,
  const float* __restrict__ eWih1, const float* __restrict__ eWhh1,
  const float* __restrict__ ebih1, const float* __restrict__ ebhh1,
  const float* __restrict__ g2eW, const float* __restrict__ htW, const float* __restrict__ dtW,
  bf16* __restrict__ W0i, bf16* __restrict__ W0r, bf16* __restrict__ W1c,
  float* __restrict__ gb0, float* __restrict__ gb1,
  bf16* __restrict__ eW0b, bf16* __restrict__ eW1ab, bf16* __restrict__ eW1bb,
  float* __restrict__ eb0, float* __restrict__ eb1, float* __restrict__ ew0cv,
  bf16* __restrict__ g2eWb, bf16* __restrict__ htWb, bf16* __restrict__ dtWb,
  unsigned int* __restrict__ h0_u, unsigned int* __restrict__ h1_u)
{
  const int st = blockIdx.x*blockDim.x + threadIdx.x;
  const int gs = gridDim.x*blockDim.x;
  auto cvt4 = [](const float* s)->ushort4 {
    float4 f = *(const float4*)s;
    ushort4 u; u.x=f2bu(f.x); u.y=f2bu(f.y); u.z=f2bu(f.z); u.w=f2bu(f.w); return u;
  };
  for (int i4=st; i4<G4*KXP/4; i4+=gs){ int n=i4>>7, kk=(i4&127)*4; int j=n>>2, g=n&3;
      ushort4 u;
      if (kk < DD) u = cvt4(&gWih0[(size_t)(g*HG+j)*DD + kk]);
      else { u.x=u.y=u.z=u.w=0; }
      *(ushort4*)&W0i[(size_t)i4*4] = u; }
  for (int i4=st; i4<G4*HG/4; i4+=gs){ int n=i4/96, kk=(i4%96)*4; int j=n>>2, g=n&3;
      *(ushort4*)&W0r[(size_t)i4*4] = cvt4(&gWhh0[(size_t)(g*HG+j)*HG + kk]); }
  for (int i4=st; i4<G4*768/4; i4+=gs){ int n=i4/192, kk=(i4%192)*4; int j=n>>2, g=n&3;
      const float* s = (kk<HG) ? &gWih1[(size_t)(g*HG+j)*HG + kk]
                               : &gWhh1[(size_t)(g*HG+j)*HG + (kk-HG)];
      *(ushort4*)&W1c[(size_t)i4*4] = cvt4(s); }
  for (int i=st; i<G4; i+=gs){ int j=i>>2, g=i&3; int s=g*HG+j;
      gb0[i]=gbih0[s]+gbhh0[s]; gb1[i]=gbih1[s]+gbhh1[s]; }
  for (int i4=st; i4<E4*HE/4; i4+=gs){
      *(ushort4*)&eW0b [(size_t)i4*4] = cvt4(&eWhh0[(size_t)i4*4]);
      *(ushort4*)&eW1ab[(size_t)i4*4] = cvt4(&eWih1[(size_t)i4*4]);
      *(ushort4*)&eW1bb[(size_t)i4*4] = cvt4(&eWhh1[(size_t)i4*4]); }
  for (int i=st; i<E4; i+=gs){ eb0[i]=ebih0[i]+ebhh0[i]; eb1[i]=ebih1[i]+ebhh1[i];
      ew0cv[i]=eWih0[i]; }
  for (int i4=st; i4<HE*HG/4; i4+=gs)
      *(ushort4*)&g2eWb[(size_t)i4*4] = cvt4(&g2eW[(size_t)i4*4]);
  for (int i4=st; i4<128*HG/4; i4+=gs){ int i=i4*4;
      ushort4 uh, ud;
      if (i < 100*HG){ uh = cvt4(&htW[i]); ud = cvt4(&dtW[i]); }
      else { uh.x=uh.y=uh.z=uh.w=0; ud=uh; }
      *(ushort4*)&htWb[i] = uh; *(ushort4*)&dtWb[i] = ud; }
  // poison the write-once h buffers (validity backstop for un-drained flags)
  for (int i=st; i<SS*BB*HG/2; i+=gs) h0_u[i] = POISON32;
  for (int i=st; i<NSEQ*HG/2;  i+=gs) h1_u[i] = POISON32;
}

// ---------------------------------------------------------------------------
// generic MFMA GEMM body:  out[M][N] = epi( A[M][KTOT] @ Wt[N][KTOT]^T )
// ---------------------------------------------------------------------------
template<int KTOT,int BN,int WAVES_M,int WAVES_N,int EPI>
__device__ __forceinline__ void gemm_body(int bid,
    const bf16* __restrict__ A, const bf16* __restrict__ Wt,
    const float* __restrict__ bias, const int* __restrict__ mask,
    void* __restrict__ outp, int Nreal)
{
  constexpr int WMT = 128/(WAVES_M*16);
  constexpr int WNT = BN /(WAVES_N*16);
  __shared__ alignas(16) bf16 As[128][32];
  __shared__ alignas(16) bf16 Bs[BN][32];
  const int tid = threadIdx.x;
  const int bm = bid & 255, bn = bid >> 8;
  const int m0 = bm*128, n0 = bn*BN;
  const int wid = tid>>6, l = tid&63, lj = l&15, lq = l>>4;
  const int wm = wid / WAVES_N, wn = wid % WAVES_N;
  floatx4 acc[WMT][WNT] = {};
  for (int k0 = 0; k0 < KTOT; k0 += 32){
    __syncthreads();
    for (int c = tid; c < 128*4; c += 256){
      int row = c>>2, ch = c&3;
      *(uint4*)&As[row][ch*8] = *(const uint4*)&A[(size_t)(m0+row)*KTOT + k0 + ch*8];
    }
    for (int c = tid; c < BN*4; c += 256){
      int row = c>>2, ch = c&3;
      *(uint4*)&Bs[row][ch*8] = *(const uint4*)&Wt[(size_t)(n0+row)*KTOT + k0 + ch*8];
    }
    __syncthreads();
    bfrag8 af[WMT]; bfrag8 bfr[WNT];
    #pragma unroll
    for (int mi=0;mi<WMT;++mi) af[mi]  = *(const bfrag8*)&As[wm*WMT*16 + mi*16 + lj][lq*8];
    #pragma unroll
    for (int ni=0;ni<WNT;++ni) bfr[ni] = *(const bfrag8*)&Bs[wn*WNT*16 + ni*16 + lj][lq*8];
    #pragma unroll
    for (int mi=0;mi<WMT;++mi)
      #pragma unroll
      for (int ni=0;ni<WNT;++ni)
        acc[mi][ni] = MFMA16(af[mi], bfr[ni], acc[mi][ni]);
  }
  #pragma unroll
  for (int mi=0;mi<WMT;++mi){
    #pragma unroll
    for (int ni=0;ni<WNT;++ni){
      #pragma unroll
      for (int r=0;r<4;++r){
        int grow = m0 + wm*WMT*16 + mi*16 + 4*lq + r;
        int gcol = n0 + wn*WNT*16 + ni*16 + lj;
        float v = acc[mi][ni][r];
        if (EPI == 3){
          v += bias[gcol];
          int s = grow & 511, b = grow >> 9;
          ((bf16*)outp)[((size_t)s*BB + b)*G4 + gcol] = __float2bfloat16(v);
        } else {
          int s = grow & 511, b = grow >> 9;
          float mk = (s==0) ? 1.f : (float)mask[b*TT + s - 1];
          v = v*mk + bias[gcol];
          if (EPI == 1){
            ((bf16*)outp)[(size_t)grow*Nreal + gcol] = __float2bfloat16(v);
          } else {
            v = v > 0.f ? v : expm1f(v);
            if (gcol < Nreal) ((float*)outp)[(size_t)grow*Nreal + gcol] = v;
          }
        }
      }
    }
  }
}

__global__ __launch_bounds__(256) void gemm_g0(
    const bf16* __restrict__ Xb, const bf16* __restrict__ W0i,
    const float* __restrict__ gb0, bf16* __restrict__ G0t)
{
  gemm_body<KXP,128,2,2,3>(blockIdx.x, Xb, W0i, gb0, nullptr, (void*)G0t, G4);
}

__global__ __launch_bounds__(256) void gemm_proj(
    const bf16* __restrict__ h1seq, const bf16* __restrict__ g2eWb,
    const float* __restrict__ g2eb, const int* __restrict__ mask,
    bf16* __restrict__ projb)
{
  gemm_body<HG,64,4,1,1>(blockIdx.x, h1seq, g2eWb, g2eb, mask, (void*)projb, HE);
}

// ---------------------------------------------------------------------------
// persistent graph-LSTM recurrence — R13 structure with UN-DRAINED flags
// (timing hint) + poison validation (correctness backstop).
// ---------------------------------------------------------------------------
template<int IS1>
__device__ __forceinline__ void rnn_body(int bid, int tid,
    const bf16* __restrict__ G0t, const bf16* __restrict__ Wsrc,
    const float* __restrict__ gb1,
    bf16* __restrict__ h0seq, bf16* __restrict__ h1seq, unsigned int* __restrict__ flags)
{
  constexpr int KW = IS1 ? 768 : 384;
  constexpr int KF = IS1 ? 24 : 12;
  const int bl = IS1 ? bid-48 : bid;
  const int w = tid>>6, l = tid&63, lj = l&15, lq = l>>4;
  const int m0 = w*16;          // wave = batch tile
  const int n0 = bl*32;         // block's 2 N-tiles: gate cols [n0, n0+32)
  const int a  = lj>>2;         // hidden index within 4-wide quad group
  const int gl = l&3;           // gate owned by this lane (i,f,g,o)
  const bool isg = (gl==2);

  // recurrent weights in registers, pinned
  intx4 Wr0[KF], Wr1[KF];
  #pragma unroll
  for (int kf=0; kf<KF; ++kf){
    Wr0[kf] = *(const intx4*)&Wsrc[(size_t)(n0 + lj)*KW      + kf*32 + lq*8];
    Wr1[kf] = *(const intx4*)&Wsrc[(size_t)(n0 + 16 + lj)*KW + kf*32 + lq*8];
  }
  #pragma unroll
  for (int kf=0; kf<KF; ++kf)
    asm volatile("" : "+v"(Wr0[kf]), "+v"(Wr1[kf]));

  float bi0 = 0.f, bi1 = 0.f;
  if (IS1){ bi0 = gb1[n0 + 4*a + gl]; bi1 = gb1[n0 + 16 + 4*a + gl]; }

  float c0s[4]={0,0,0,0}, c1s[4]={0,0,0,0};
  unsigned short g0pre[2][4];
  if (!IS1){
    #pragma unroll
    for (int nt=0;nt<2;++nt)
      #pragma unroll
      for (int r=0;r<4;++r)
        g0pre[nt][r] = *(const unsigned short*)&G0t[(size_t)(m0 + 4*lq + r)*G4 + n0 + nt*16 + 4*a + gl];
  }
  // flag pointers: layout flags[(layer*48 + bl)*4 + w], 16 u32 per line
  unsigned int* myflag = flags + (size_t)(((IS1?48:0) + bl)*4 + w)*16;
  unsigned int* f0p = flags + (size_t)((l)*4 + w)*16;          // L0 flags, lane l<48
  unsigned int* f1p = flags + (size_t)((48 + l)*4 + w)*16;     // L1 flags, lane l<48

  const int ITMAX = IS1 ? SS : (SS-1);
  for (int it=0; it<=ITMAX; ++it){
    // ---- wait phase (timing hint; lanes 0..47 poll distinct flag lines) ----
    if (it >= 1){
      const unsigned tgt = (unsigned)it;
      const bool need = (l < 48);
      while (true){
        bool ok = true;
        if (need){
          unsigned f0 = __hip_atomic_load(f0p, __ATOMIC_RELAXED, __HIP_MEMORY_SCOPE_AGENT);
          ok = (f0 >= tgt);
          if (IS1){
            unsigned f1 = __hip_atomic_load(f1p, __ATOMIC_RELAXED, __HIP_MEMORY_SCOPE_AGENT);
            ok = ok && (f1 >= tgt);
          }
        }
        if (__all(ok)) break;
        __builtin_amdgcn_s_sleep(1);
      }
      asm volatile("" ::: "memory");   // compiler fence (reduces first-pass misses)
    }
    // ---- compute phase (poison-validated loads = correctness) ----
    if (!IS1 || it >= 1){
      const int t = IS1 ? it-1 : it;
      intx4 ha[KF];
      if (IS1){
        const bf16* hb0 = h0seq + ((size_t)t*BB + (m0+lj))*HG;
        if (t > 0){
          const bf16* hb1 = h1seq + ((size_t)(m0+lj)*SS + (t-1))*HG;
          load24_chk(hb0, hb1, lq, ha);
        } else {
          loadN_chk<12>(hb0, lq, ha);
        }
      } else if (t > 0){
        const bf16* hb = h0seq + ((size_t)(t-1)*BB + (m0+lj))*HG;
        loadN_chk<12>(hb, lq, ha);
      }
      floatx4 aA0={0,0,0,0}, aB0={0,0,0,0}, aA1={0,0,0,0}, aB1={0,0,0,0};
      if (IS1 || t > 0){
        #pragma unroll
        for (int kf=0;kf<12;++kf){
          if (kf&1){ aB0 = MFMA16(asfrag(ha[kf]), asfrag(Wr0[kf]), aB0); aB1 = MFMA16(asfrag(ha[kf]), asfrag(Wr1[kf]), aB1); }
          else     { aA0 = MFMA16(asfrag(ha[kf]), asfrag(Wr0[kf]), aA0); aA1 = MFMA16(asfrag(ha[kf]), asfrag(Wr1[kf]), aA1); }
        }
      }
      if (IS1 && t > 0){
        #pragma unroll
        for (int kf=12;kf<24;++kf){
          if (kf&1){ aB0 = MFMA16(asfrag(ha[kf]), asfrag(Wr0[kf]), aB0); aB1 = MFMA16(asfrag(ha[kf]), asfrag(Wr1[kf]), aB1); }
          else     { aA0 = MFMA16(asfrag(ha[kf]), asfrag(Wr0[kf]), aA0); aA1 = MFMA16(asfrag(ha[kf]), asfrag(Wr1[kf]), aA1); }
        }
      }
      const floatx4 s0 = aA0 + aB0, s1 = aA1 + aB1;
      #pragma unroll
      for (int nt=0; nt<2; ++nt){
        #pragma unroll
        for (int r=0; r<4; ++r){
          float x = nt ? s1[r] : s0[r];
          x += IS1 ? (nt ? bi1 : bi0) : b2f(g0pre[nt][r]);
          float av = actv(x, isg);            // own gate only
          float i_ = __shfl(av, (l&60)|0);
          float f_ = __shfl(av, (l&60)|1);
          float g_ = __shfl(av, (l&60)|2);
          float o_ = __shfl(av, (l&60)|3);
          float cp = nt ? c1s[r] : c0s[r];
          float c = f_*cp + i_*g_;
          if (nt) c1s[r] = c; else c0s[r] = c;
          float h = o_*tanh_(c);
          float hn = __shfl(h, l^4);          // neighbor quad's h (a+1)
          if ((l&7) == 0){
            int bb = m0 + 4*lq + r;
            int jh = bl*8 + nt*4 + a;         // a even here
            bf16* hp = IS1 ? (h1seq + ((size_t)bb*SS + t)*HG + jh)
                           : (h0seq + ((size_t)t*BB + bb)*HG + jh);
            stpair_coh(hp, h, hn);
          }
        }
      }
    }
    // ---- signal phase: UN-DRAINED flag (data validity via poison) ----
    __builtin_amdgcn_sched_barrier(0);
    asm volatile("" ::: "memory");
    if (l == 0)
      __hip_atomic_store(myflag, (unsigned)(it+1),
                         __ATOMIC_RELAXED, __HIP_MEMORY_SCOPE_AGENT);
    // prefetch next round's G0 pre-acts (read-only, off the signal path)
    if (!IS1 && it+1 <= ITMAX){
      #pragma unroll
      for (int nt=0;nt<2;++nt)
        #pragma unroll
        for (int r=0;r<4;++r)
          g0pre[nt][r] = *(const unsigned short*)&G0t[((size_t)(it+1)*BB + m0 + 4*lq + r)*G4 + n0 + nt*16 + 4*a + gl];
    }
  }
}

__global__ __launch_bounds__(256,1) void graph_rnn(
    const bf16* __restrict__ G0t, const bf16* __restrict__ W0r, const bf16* __restrict__ W1c,
    const float* __restrict__ gb1, bf16* __restrict__ h0seq, bf16* __restrict__ h1seq,
    unsigned int* flags)
{
  if (blockIdx.x < 48) rnn_body<0>(blockIdx.x, threadIdx.x, G0t, W0r, gb1, h0seq, h1seq, flags);
  else                 rnn_body<1>(blockIdx.x, threadIdx.x, G0t, W1c, gb1, h0seq, h1seq, flags);
}

// ---------------------------------------------------------------------------
// fused 2-layer edge LSTM body (blocks 0..2047) + tag FFs (blocks 2048..2559)
// ---------------------------------------------------------------------------
__device__ void edge_body(int bid,
    const bf16* __restrict__ projb,
    const bf16* __restrict__ eW0b, const bf16* __restrict__ eW1ab, const bf16* __restrict__ eW1bb,
    const float* __restrict__ eb0, const float* __restrict__ eb1, const float* __restrict__ ew0c,
    const float* __restrict__ clsW, const float* __restrict__ clsb_p, const float* __restrict__ bos_p,
    const int* __restrict__ heads, float* __restrict__ arc)
{
  __shared__ alignas(16) bf16 hbuf0[16][72];
  __shared__ alignas(16) bf16 hbuf1[16][72];
  __shared__ float lbuf[4][16];
  const int tid = threadIdx.x, w = tid>>6, l = tid&63, lj = l&15, lq = l>>4;
  const int seq0 = bid * 16;
  const int jglob = w*16 + lj;
  for (int i = tid; i < 16*64; i += 256){
    int sl = i >> 6, jj = i & 63;
    bf16 v = projb[(size_t)(seq0+sl)*HE + jj];
    hbuf0[sl][jj] = v; hbuf1[sl][jj] = v;
  }
  bfrag8 W0f[4][2], W1af[4][2], W1bf[4][2];
  #pragma unroll
  for (int g=0; g<4; ++g){
    #pragma unroll
    for (int kk=0; kk<2; ++kk){
      size_t offw = (size_t)(g*HE + jglob)*HE + kk*32 + lq*8;
      W0f [g][kk] = *(const bfrag8*)&eW0b [offw];
      W1af[g][kk] = *(const bfrag8*)&eW1ab[offw];
      W1bf[g][kk] = *(const bfrag8*)&eW1bb[offw];
    }
  }
  float ebr0[4], ebr1[4], ewr[4];
  #pragma unroll
  for (int g=0; g<4; ++g){ ebr0[g]=eb0[g*HE+jglob]; ebr1[g]=eb1[g*HE+jglob]; ewr[g]=ew0c[g*HE+jglob]; }
  const float clswj = clsW[jglob];
  const float bos = bos_p[0], clsb = clsb_p[0];
  int hd[4]; float c0r[4]={0,0,0,0}, c1r[4]={0,0,0,0};
  #pragma unroll
  for (int r=0;r<4;++r){
    int sq = seq0 + 4*lq + r;
    int b = sq >> 9, s = sq & 511;
    hd[r] = (s==0) ? 0 : heads[b*TT + s - 1];
  }
  __syncthreads();
  for (int j=0; j<33; ++j){
    floatx4 acc0[4] = {};
    bfrag8 a0[2];
    #pragma unroll
    for (int kk=0; kk<2; ++kk)
      a0[kk] = *(const bfrag8*)((const char*)&hbuf0[0][0] + lj*144 + kk*64 + lq*16);
    #pragma unroll
    for (int g=0; g<4; ++g)
      #pragma unroll
      for (int kk=0; kk<2; ++kk)
        acc0[g] = MFMA16(a0[kk], W0f[g][kk], acc0[g]);
    __syncthreads();
    float h0v[4];
    #pragma unroll
    for (int r=0;r<4;++r){
      float x = (j==0) ? bos : ((hd[r] == j-1) ? 1.f : 0.f);
      float pi = acc0[0][r] + ebr0[0] + x*ewr[0];
      float pf = acc0[1][r] + ebr0[1] + x*ewr[1];
      float pg = acc0[2][r] + ebr0[2] + x*ewr[2];
      float po = acc0[3][r] + ebr0[3] + x*ewr[3];
      float i_=sigm_(pi), f_=sigm_(pf), g_=tanh_(pg), o_=sigm_(po);
      c0r[r] = f_*c0r[r] + i_*g_;
      h0v[r] = o_*tanh_(c0r[r]);
    }
    #pragma unroll
    for (int r=0;r<4;++r) hbuf0[4*lq + r][jglob] = __float2bfloat16(h0v[r]);
    __syncthreads();
    floatx4 acc1[4] = {};
    bfrag8 a1[2], a2[2];
    #pragma unroll
    for (int kk=0;kk<2;++kk){
      a1[kk] = *(const bfrag8*)((const char*)&hbuf0[0][0] + lj*144 + kk*64 + lq*16);
      a2[kk] = *(const bfrag8*)((const char*)&hbuf1[0][0] + lj*144 + kk*64 + lq*16);
    }
    #pragma unroll
    for (int g=0; g<4; ++g){
      #pragma unroll
      for (int kk=0;kk<2;++kk){
        acc1[g] = MFMA16(a1[kk], W1af[g][kk], acc1[g]);
        acc1[g] = MFMA16(a2[kk], W1bf[g][kk], acc1[g]);
      }
    }
    __syncthreads();
    float p[4];
    #pragma unroll
    for (int r=0;r<4;++r){
      float pi = acc1[0][r] + ebr1[0];
      float pf = acc1[1][r] + ebr1[1];
      float pg = acc1[2][r] + ebr1[2];
      float po = acc1[3][r] + ebr1[3];
      float i_=sigm_(pi), f_=sigm_(pf), g_=tanh_(pg), o_=sigm_(po);
      c1r[r] = f_*c1r[r] + i_*g_;
      float h1 = o_*tanh_(c1r[r]);
      hbuf1[4*lq + r][jglob] = __float2bfloat16(h1);
      p[r] = h1 * clswj;
    }
    #pragma unroll
    for (int mk=1; mk<16; mk<<=1)
      #pragma unroll
      for (int r=0;r<4;++r) p[r] += __shfl_xor(p[r], mk, 64);
    if (lj == 0){
      #pragma unroll
      for (int r=0;r<4;++r) lbuf[w][4*lq + r] = p[r];
    }
    __syncthreads();
    if (tid < 16 && j >= 1){
      int sq = seq0 + tid;
      float v = lbuf[0][tid] + lbuf[1][tid] + lbuf[2][tid] + lbuf[3][tid] + clsb;
      arc[(size_t)sq*SS + (j-1)] = v;
    }
  }
}

__global__ __launch_bounds__(256) void edge_tag(
    const bf16* __restrict__ projb,
    const bf16* __restrict__ eW0b, const bf16* __restrict__ eW1ab, const bf16* __restrict__ eW1bb,
    const float* __restrict__ eb0, const float* __restrict__ eb1, const float* __restrict__ ew0c,
    const float* __restrict__ clsW, const float* __restrict__ clsb_p, const float* __restrict__ bos_p,
    const int* __restrict__ heads, float* __restrict__ arc,
    const bf16* __restrict__ h1seq,
    const bf16* __restrict__ htWb, const float* __restrict__ htb,
    const bf16* __restrict__ dtWb, const float* __restrict__ dtb,
    const int* __restrict__ mask, float* __restrict__ out_ht, float* __restrict__ out_dt)
{
  const int b = blockIdx.x;
  if (b < 2048)      edge_body(b, projb, eW0b, eW1ab, eW1bb, eb0, eb1, ew0c,
                               clsW, clsb_p, bos_p, heads, arc);
  else if (b < 2304) gemm_body<HG,128,2,2,2>(b-2048, h1seq, htWb, htb, mask, (void*)out_ht, 100);
  else               gemm_body<HG,128,2,2,2>(b-2304, h1seq, dtWb, dtb, mask, (void*)out_dt, 100);
}

// ---------------------------------------------------------------------------
extern "C" void kernel_launch(void* const* d_in, const int* in_sizes, int n_in,
                              void* d_out, int out_size, void* d_ws, size_t ws_size,
                              hipStream_t stream)
{
  const float* input = (const float*)d_in[0];
  const float* tag   = (const float*)d_in[1];
  const int*   mask  = (const int*)  d_in[2];
  const int*   heads = (const int*)  d_in[3];
  const float* sent  = (const float*)d_in[4];
  const float* bosp  = (const float*)d_in[5];
  const float* gWih0 = (const float*)d_in[6];
  const float* gWhh0 = (const float*)d_in[7];
  const float* gbih0 = (const float*)d_in[8];
  const float* gbhh0 = (const float*)d_in[9];
  const float* gWih1 = (const float*)d_in[10];
  const float* gWhh1 = (const float*)d_in[11];
  const float* gbih1 = (const float*)d_in[12];
  const float* gbhh1 = (const float*)d_in[13];
  const float* eWih0 = (const float*)d_in[14];
  const float* eWhh0 = (const float*)d_in[15];
  const float* ebih0 = (const float*)d_in[16];
  const float* ebhh0 = (const float*)d_in[17];
  const float* eWih1 = (const float*)d_in[18];
  const float* eWhh1 = (const float*)d_in[19];
  const float* ebih1 = (const float*)d_in[20];
  const float* ebhh1 = (const float*)d_in[21];
  const float* g2eW  = (const float*)d_in[22];
  const float* g2eb  = (const float*)d_in[23];
  const float* clsW  = (const float*)d_in[24];
  const float* clsb  = (const float*)d_in[25];
  const float* htW   = (const float*)d_in[26];
  const float* htb   = (const float*)d_in[27];
  const float* dtW   = (const float*)d_in[28];
  const float* dtb   = (const float*)d_in[29];

  char* wsb = (char*)d_ws;
  size_t off = 0;
  auto take = [&](size_t bytes)->char* {
    char* p = wsb + off;
    off = (off + bytes + 255) & ~(size_t)255;
    return p;
  };
  bf16*  Xb     = (bf16*) take((size_t)NSEQ*KXP*2);   // 33.6 MB
  bf16*  W0i    = (bf16*) take((size_t)G4*KXP*2);     // interleaved Wih0
  bf16*  W0r    = (bf16*) take((size_t)G4*HG*2);      // interleaved Whh0
  bf16*  W1c    = (bf16*) take((size_t)G4*768*2);     // interleaved [Wih1|Whh1]
  float* gb0i   = (float*)take(G4*4);
  float* gb1i   = (float*)take(G4*4);
  bf16*  G0t    = (bf16*) take((size_t)NSEQ*G4*2);    // 100.7 MB, time-major [t][b][1536]
  bf16*  h0seq  = (bf16*) take((size_t)SS*BB*HG*2);   // 25.2 MB [t][b][384], write-once, poisoned
  bf16*  h1seq  = (bf16*) take((size_t)NSEQ*HG*2);    // 25.2 MB [b][t][384], write-once, poisoned
  unsigned int* flags = (unsigned int*)take(384*16*4);// 384 per-wave flag lines (64B each)
  bf16*  projb  = (bf16*) take((size_t)NSEQ*HE*2);
  bf16*  eW0b   = (bf16*) take(E4*HE*2);
  bf16*  eW1ab  = (bf16*) take(E4*HE*2);
  bf16*  eW1bb  = (bf16*) take(E4*HE*2);
  float* eb0w   = (float*)take(E4*4);
  float* eb1w   = (float*)take(E4*4);
  float* ew0cw  = (float*)take(E4*4);
  bf16*  g2eWb  = (bf16*) take(HE*HG*2);
  bf16*  htWb   = (bf16*) take(128*HG*2);
  bf16*  dtWb   = (bf16*) take(128*HG*2);

  (void)hipMemsetAsync(d_out, 0, (size_t)16777216*4, stream);
  (void)hipMemsetAsync(flags, 0, 384*16*4, stream);

  prep_x<<<2048,256,0,stream>>>(input, tag, sent, Xb);
  prep_w<<<512,256,0,stream>>>(gWih0,gWhh0,gbih0,gbhh0,gWih1,gWhh1,gbih1,gbhh1,
                               eWih0,eWhh0,ebih0,ebhh0,eWih1,eWhh1,ebih1,ebhh1,
                               g2eW,htW,dtW,
                               W0i,W0r,W1c,gb0i,gb1i,eW0b,eW1ab,eW1bb,
                               eb0w,eb1w,ew0cw,g2eWb,htWb,dtWb,
                               (unsigned int*)h0seq, (unsigned int*)h1seq);

  // layer-0 input gates, time-major (plain coalesced stores)
  gemm_g0<<<3072,256,0,stream>>>(Xb, W0i, gb0i, G0t);

  // persistent 2-layer recurrence — un-drained flags + poison backstop
  graph_rnn<<<96,256,0,stream>>>(G0t, W0r, W1c, gb1i, h0seq, h1seq, flags);

  // proj (must precede edge_tag)
  gemm_proj<<<256,256,0,stream>>>(h1seq, g2eWb, g2eb, mask, projb);

  // edge LSTM + both tag FFs fused (tags overlap the edge recurrence)
  edge_tag<<<2560,256,0,stream>>>(projb, eW0b, eW1ab, eW1bb, eb0w, eb1w, ew0cw,
                                  clsW, clsb, bosp, heads, (float*)d_out,
                                  h1seq, htWb, htb, dtWb, dtb, mask,
                                  (float*)d_out + 16777216,
                                  (float*)d_out + 16777216 + 3276800);
}

// Round 15
// 4857.215 us; speedup vs baseline: 1.0131x; 1.0131x over previous
//
#include <hip/hip_runtime.h>
#include <hip/hip_bf16.h>
#include <stdint.h>

// ---------------- problem dims ----------------
#define BB   64
#define TT   511
#define SS   512
#define DD   500
#define KXP  512          // padded input dim for layer-0 input GEMM
#define HG   384
#define G4   1536
#define HE   64
#define E4   256
#define NSEQ (BB*SS)      // 32768

typedef __hip_bfloat16 bf16;
typedef float  floatx4 __attribute__((ext_vector_type(4)));
typedef int    intx4   __attribute__((ext_vector_type(4)));
typedef __bf16 bfrag8  __attribute__((ext_vector_type(8)));
typedef unsigned short ushort8 __attribute__((ext_vector_type(8)));

// v_mfma_f32_16x16x32_bf16 fragment layout (gfx950):
//   A: lane l holds A[l&15][8*(l>>4)+i]      (16B contiguous along K, A stored [M][K])
//   B: lane l holds W[n=l&15][8*(l>>4)+i]    (weights stored [N][K] = torch [out][in])
//   D: lane l, reg r holds D[4*(l>>4)+r][l&15]
static __device__ __forceinline__ floatx4 MFMA16(bfrag8 a, bfrag8 b, floatx4 c){
  return __builtin_amdgcn_mfma_f32_16x16x32_bf16(a, b, c, 0, 0, 0);
}
static __device__ __forceinline__ float sigm_(float x){ return 1.f/(1.f + __expf(-x)); }
static __device__ __forceinline__ float tanh_(float x){
  x = fminf(fmaxf(x, -15.f), 15.f);
  float e = __expf(2.f*x);
  return (e - 1.f)/(e + 1.f);
}
// per-lane gate activation: sigm for i,f,o; tanh via 2*sigm(2x)-1 for g
static __device__ __forceinline__ float actv(float x, bool isg){
  float s = 1.f/(1.f + __expf(isg ? -2.f*x : -x));
  return isg ? (2.f*s - 1.f) : s;
}
static __device__ __forceinline__ float b2f(unsigned short u){
  union { unsigned int i; float f; } x; x.i = ((unsigned int)u)<<16; return x.f;
}
static __device__ __forceinline__ unsigned short f2bu(float f){
  bf16 b = __float2bfloat16(f);
  return *reinterpret_cast<unsigned short*>(&b);
}
static __device__ __forceinline__ bfrag8 asfrag(intx4 v){
  union { intx4 i; bfrag8 f; } u; u.i = v; return u.f;
}

// ---- coherence-point accesses for cross-block RNN state (HIP atomics) ----
static __device__ __forceinline__ bfrag8 ldfrag_coh(const bf16* p){
  unsigned long long u0 = __hip_atomic_load((const unsigned long long*)p,     __ATOMIC_RELAXED, __HIP_MEMORY_SCOPE_SYSTEM);
  unsigned long long u1 = __hip_atomic_load((const unsigned long long*)p + 1, __ATOMIC_RELAXED, __HIP_MEMORY_SCOPE_SYSTEM);
  union { unsigned long long u[2]; bfrag8 f; } x; x.u[0]=u0; x.u[1]=u1;
  return x.f;
}
static __device__ __forceinline__ void stpair_coh(bf16* p, float lo, float hi){
  unsigned int pk = (unsigned int)f2bu(lo) | ((unsigned int)f2bu(hi) << 16);
  __hip_atomic_store((unsigned int*)p, pk, __ATOMIC_RELAXED, __HIP_MEMORY_SCOPE_SYSTEM);
}

// ---------------------------------------------------------------------------
// prep: build padded bf16 X = [sentinel ; concat(input, tag)]  -> [32768][512]
// 8-wide vectorized (float4 reads, bf16x8 writes)
// ---------------------------------------------------------------------------
__global__ __launch_bounds__(256) void prep_x(const float* __restrict__ input,
    const float* __restrict__ tag, const float* __restrict__ sent,
    bf16* __restrict__ Xb)
{
  const size_t N8 = (size_t)NSEQ*KXP/8;
  const size_t stp = (size_t)gridDim.x * blockDim.x;
  for (size_t i8 = (size_t)blockIdx.x*blockDim.x + threadIdx.x; i8 < N8; i8 += stp){
    int m = (int)(i8 >> 6);
    int k = ((int)i8 & 63) * 8;
    int b = m >> 9, s = m & 511;
    float v[8];
    if (s == 0){
      #pragma unroll
      for (int j=0;j<8;++j) v[j] = (k+j < DD) ? sent[k+j] : 0.f;
    } else if (k < 400){
      const float* src = input + (size_t)(b*TT + s-1)*400 + k;
      float4 a = *(const float4*)src;
      float4 c = *(const float4*)(src+4);
      v[0]=a.x; v[1]=a.y; v[2]=a.z; v[3]=a.w; v[4]=c.x; v[5]=c.y; v[6]=c.z; v[7]=c.w;
    } else if (k < 496){
      const float* src = tag + (size_t)(b*TT + s-1)*100 + (k-400);
      float4 a = *(const float4*)src;
      float4 c = *(const float4*)(src+4);
      v[0]=a.x; v[1]=a.y; v[2]=a.z; v[3]=a.w; v[4]=c.x; v[5]=c.y; v[6]=c.z; v[7]=c.w;
    } else if (k == 496){
      const float* src = tag + (size_t)(b*TT + s-1)*100 + 96;
      float4 a = *(const float4*)src;
      v[0]=a.x; v[1]=a.y; v[2]=a.z; v[3]=a.w; v[4]=0.f; v[5]=0.f; v[6]=0.f; v[7]=0.f;
    } else {
      #pragma unroll
      for (int j=0;j<8;++j) v[j]=0.f;
    }
    ushort8 o;
    #pragma unroll
    for (int j=0;j<8;++j) o[j] = f2bu(v[j]);
    *(ushort8*)&Xb[i8*8] = o;
  }
}

// ---------------------------------------------------------------------------
// prep: weight conversions with gate interleave n=4j+g, bias folds (4-wide)
// ---------------------------------------------------------------------------
__global__ __launch_bounds__(256) void prep_w(
  const float* __restrict__ gWih0, const float* __restrict__ gWhh0,
  const float* __restrict__ gbih0, const float* __restrict__ gbhh0,
  const float* __restrict__ gWih1, const float* __restrict__ gWhh1,
  const float* __restrict__ gbih1, const float* __restrict__ gbhh1,
  const float* __restrict__ eWih0, const float* __restrict__ eWhh0,
  const float* __restrict__ ebih0, const float* __restrict__ ebhh0,
  const float* __restrict__ eWih1, const float* __restrict__ eWhh1,
  const float* __restrict__ ebih1, const float* __restrict__ ebhh1,
  const float* __restrict__ g2eW, const float* __restrict__ htW, const float* __restrict__ dtW,
  bf16* __restrict__ W0i, bf16* __restrict__ W0r, bf16* __restrict__ W1c,
  float* __restrict__ gb0, float* __restrict__ gb1,
  bf16* __restrict__ eW0b, bf16* __restrict__ eW1ab, bf16* __restrict__ eW1bb,
  float* __restrict__ eb0, float* __restrict__ eb1, float* __restrict__ ew0cv,
  bf16* __restrict__ g2eWb, bf16* __restrict__ htWb, bf16* __restrict__ dtWb)
{
  const int st = blockIdx.x*blockDim.x + threadIdx.x;
  const int gs = gridDim.x*blockDim.x;
  auto cvt4 = [](const float* s)->ushort4 {
    float4 f = *(const float4*)s;
    ushort4 u; u.x=f2bu(f.x); u.y=f2bu(f.y); u.z=f2bu(f.z); u.w=f2bu(f.w); return u;
  };
  // W0i: [1536][512], rows n=4j+g, K padded (500->512)
  for (int i4=st; i4<G4*KXP/4; i4+=gs){ int n=i4>>7, kk=(i4&127)*4; int j=n>>2, g=n&3;
      ushort4 u;
      if (kk < DD) u = cvt4(&gWih0[(size_t)(g*HG+j)*DD + kk]);
      else { u.x=u.y=u.z=u.w=0; }
      *(ushort4*)&W0i[(size_t)i4*4] = u; }
  // W0r: [1536][384]
  for (int i4=st; i4<G4*HG/4; i4+=gs){ int n=i4/96, kk=(i4%96)*4; int j=n>>2, g=n&3;
      *(ushort4*)&W0r[(size_t)i4*4] = cvt4(&gWhh0[(size_t)(g*HG+j)*HG + kk]); }
  // W1c: [1536][768] = [Wih1 | Whh1]
  for (int i4=st; i4<G4*768/4; i4+=gs){ int n=i4/192, kk=(i4%192)*4; int j=n>>2, g=n&3;
      const float* s = (kk<HG) ? &gWih1[(size_t)(g*HG+j)*HG + kk]
                               : &gWhh1[(size_t)(g*HG+j)*HG + (kk-HG)];
      *(ushort4*)&W1c[(size_t)i4*4] = cvt4(s); }
  for (int i=st; i<G4; i+=gs){ int j=i>>2, g=i&3; int s=g*HG+j;
      gb0[i]=gbih0[s]+gbhh0[s]; gb1[i]=gbih1[s]+gbhh1[s]; }
  // edge LSTM weights
  for (int i4=st; i4<E4*HE/4; i4+=gs){
      *(ushort4*)&eW0b [(size_t)i4*4] = cvt4(&eWhh0[(size_t)i4*4]);
      *(ushort4*)&eW1ab[(size_t)i4*4] = cvt4(&eWih1[(size_t)i4*4]);
      *(ushort4*)&eW1bb[(size_t)i4*4] = cvt4(&eWhh1[(size_t)i4*4]); }
  for (int i=st; i<E4; i+=gs){ eb0[i]=ebih0[i]+ebhh0[i]; eb1[i]=ebih1[i]+ebhh1[i];
      ew0cv[i]=eWih0[i]; }
  for (int i4=st; i4<HE*HG/4; i4+=gs)
      *(ushort4*)&g2eWb[(size_t)i4*4] = cvt4(&g2eW[(size_t)i4*4]);
  for (int i4=st; i4<128*HG/4; i4+=gs){ int i=i4*4;
      ushort4 uh, ud;
      if (i < 100*HG){ uh = cvt4(&htW[i]); ud = cvt4(&dtW[i]); }
      else { uh.x=uh.y=uh.z=uh.w=0; ud=uh; }
      *(ushort4*)&htWb[i] = uh; *(ushort4*)&dtWb[i] = ud; }
}

// ---------------------------------------------------------------------------
// generic MFMA GEMM body:  out[M][N] = epi( A[M][KTOT] @ Wt[N][KTOT]^T )
//   EPI 1: *maskrow +bias, store bf16
//   EPI 2: *maskrow +bias, elu, store f32, guard col<Nreal
//   EPI 3: +bias, store bf16 TRANSPOSED time-major: out[(s*64+b)*1536 + col]
// ---------------------------------------------------------------------------
template<int KTOT,int BN,int WAVES_M,int WAVES_N,int EPI>
__device__ __forceinline__ void gemm_body(int bid,
    const bf16* __restrict__ A, const bf16* __restrict__ Wt,
    const float* __restrict__ bias, const int* __restrict__ mask,
    void* __restrict__ outp, int Nreal)
{
  constexpr int WMT = 128/(WAVES_M*16);
  constexpr int WNT = BN /(WAVES_N*16);
  __shared__ alignas(16) bf16 As[128][32];
  __shared__ alignas(16) bf16 Bs[BN][32];
  const int tid = threadIdx.x;
  const int bm = bid & 255, bn = bid >> 8;
  const int m0 = bm*128, n0 = bn*BN;
  const int wid = tid>>6, l = tid&63, lj = l&15, lq = l>>4;
  const int wm = wid / WAVES_N, wn = wid % WAVES_N;
  floatx4 acc[WMT][WNT] = {};
  for (int k0 = 0; k0 < KTOT; k0 += 32){
    __syncthreads();
    for (int c = tid; c < 128*4; c += 256){
      int row = c>>2, ch = c&3;
      *(uint4*)&As[row][ch*8] = *(const uint4*)&A[(size_t)(m0+row)*KTOT + k0 + ch*8];
    }
    for (int c = tid; c < BN*4; c += 256){
      int row = c>>2, ch = c&3;
      *(uint4*)&Bs[row][ch*8] = *(const uint4*)&Wt[(size_t)(n0+row)*KTOT + k0 + ch*8];
    }
    __syncthreads();
    bfrag8 af[WMT]; bfrag8 bfr[WNT];
    #pragma unroll
    for (int mi=0;mi<WMT;++mi) af[mi]  = *(const bfrag8*)&As[wm*WMT*16 + mi*16 + lj][lq*8];
    #pragma unroll
    for (int ni=0;ni<WNT;++ni) bfr[ni] = *(const bfrag8*)&Bs[wn*WNT*16 + ni*16 + lj][lq*8];
    #pragma unroll
    for (int mi=0;mi<WMT;++mi)
      #pragma unroll
      for (int ni=0;ni<WNT;++ni)
        acc[mi][ni] = MFMA16(af[mi], bfr[ni], acc[mi][ni]);
  }
  #pragma unroll
  for (int mi=0;mi<WMT;++mi){
    #pragma unroll
    for (int ni=0;ni<WNT;++ni){
      #pragma unroll
      for (int r=0;r<4;++r){
        int grow = m0 + wm*WMT*16 + mi*16 + 4*lq + r;
        int gcol = n0 + wn*WNT*16 + ni*16 + lj;
        float v = acc[mi][ni][r];
        if (EPI == 3){
          v += bias[gcol];
          int s = grow & 511, b = grow >> 9;
          ((bf16*)outp)[((size_t)s*BB + b)*G4 + gcol] = __float2bfloat16(v);
        } else {
          int s = grow & 511, b = grow >> 9;
          float mk = (s==0) ? 1.f : (float)mask[b*TT + s - 1];
          v = v*mk + bias[gcol];
          if (EPI == 1){
            ((bf16*)outp)[(size_t)grow*Nreal + gcol] = __float2bfloat16(v);
          } else {
            v = v > 0.f ? v : expm1f(v);
            if (gcol < Nreal) ((float*)outp)[(size_t)grow*Nreal + gcol] = v;
          }
        }
      }
    }
  }
}

// G0 GEMM (separate kernel, plain coalesced stores; kernel boundary = fence)
__global__ __launch_bounds__(256) void gemm_g0(
    const bf16* __restrict__ Xb, const bf16* __restrict__ W0i,
    const float* __restrict__ gb0, bf16* __restrict__ G0t)
{
  gemm_body<KXP,128,2,2,3>(blockIdx.x, Xb, W0i, gb0, nullptr, (void*)G0t, G4);
}

// proj kernel (must finish before edge_lstm reads projb)
__global__ __launch_bounds__(256) void gemm_proj(
    const bf16* __restrict__ h1seq, const bf16* __restrict__ g2eWb,
    const float* __restrict__ g2eb, const int* __restrict__ mask,
    bf16* __restrict__ projb)
{
  gemm_body<HG,64,4,1,1>(blockIdx.x, h1seq, g2eWb, g2eb, mask, (void*)projb, HE);
}

// ---------------------------------------------------------------------------
// persistent graph-LSTM recurrence — per-wave flags, write-once h buffers.
// 96 blocks x 256 thr; blocks 0..47 layer0 (t=it, rounds 0..511),
// blocks 48..95 layer1 (t=it-1, rounds 0..512). Wave w of block bl owns
// batch rows [w*16,w*16+16) x gate cols [bl*32,bl*32+32).
//  * flags[(layer*48+bl)*4+w] published per-wave after s_waitcnt vmcnt(0).
//  * consumer wave w polls its 48 (+48 for L1) same-w producer flags.
//  * asm "" memory clobber after the poll = compiler fence (no load hoist).
// Structural floor: 5 sync protocols converge at ~8.4 µs/round — the
// cross-XCD Infinity-Cache handoff latency of a 513-deep dependent chain.
// ---------------------------------------------------------------------------
template<int IS1>
__device__ __forceinline__ void rnn_body(int bid, int tid,
    const bf16* __restrict__ G0t, const bf16* __restrict__ Wsrc,
    const float* __restrict__ gb1,
    bf16* __restrict__ h0seq, bf16* __restrict__ h1seq, unsigned int* __restrict__ flags)
{
  constexpr int KW = IS1 ? 768 : 384;
  constexpr int KF = IS1 ? 24 : 12;
  const int bl = IS1 ? bid-48 : bid;
  const int w = tid>>6, l = tid&63, lj = l&15, lq = l>>4;
  const int m0 = w*16;          // wave = batch tile
  const int n0 = bl*32;         // block's 2 N-tiles: gate cols [n0, n0+32)
  const int a  = lj>>2;         // hidden index within 4-wide quad group
  const int gl = l&3;           // gate owned by this lane (i,f,g,o)
  const bool isg = (gl==2);

  // recurrent weights in registers, pinned
  intx4 Wr0[KF], Wr1[KF];
  #pragma unroll
  for (int kf=0; kf<KF; ++kf){
    Wr0[kf] = *(const intx4*)&Wsrc[(size_t)(n0 + lj)*KW      + kf*32 + lq*8];
    Wr1[kf] = *(const intx4*)&Wsrc[(size_t)(n0 + 16 + lj)*KW + kf*32 + lq*8];
  }
  #pragma unroll
  for (int kf=0; kf<KF; ++kf)
    asm volatile("" : "+v"(Wr0[kf]), "+v"(Wr1[kf]));

  float bi0 = 0.f, bi1 = 0.f;
  if (IS1){ bi0 = gb1[n0 + 4*a + gl]; bi1 = gb1[n0 + 16 + 4*a + gl]; }

  float c0s[4]={0,0,0,0}, c1s[4]={0,0,0,0};
  unsigned short g0pre[2][4];
  if (!IS1){
    #pragma unroll
    for (int nt=0;nt<2;++nt)
      #pragma unroll
      for (int r=0;r<4;++r)
        g0pre[nt][r] = *(const unsigned short*)&G0t[(size_t)(m0 + 4*lq + r)*G4 + n0 + nt*16 + 4*a + gl];
  }
  // flag pointers: layout flags[(layer*48 + bl)*4 + w], 16 u32 per line
  unsigned int* myflag = flags + (size_t)(((IS1?48:0) + bl)*4 + w)*16;
  unsigned int* f0p = flags + (size_t)((l)*4 + w)*16;          // L0 flags, lane l<48
  unsigned int* f1p = flags + (size_t)((48 + l)*4 + w)*16;     // L1 flags, lane l<48

  const int ITMAX = IS1 ? SS : (SS-1);
  for (int it=0; it<=ITMAX; ++it){
    // ---- wait phase (per-wave; lanes 0..47 poll distinct flag lines) ----
    if (it >= 1){
      const unsigned tgt = (unsigned)it;
      const bool need = (l < 48);
      while (true){
        bool ok = true;
        if (need){
          unsigned f0 = __hip_atomic_load(f0p, __ATOMIC_RELAXED, __HIP_MEMORY_SCOPE_AGENT);
          ok = (f0 >= tgt);
          if (IS1){
            unsigned f1 = __hip_atomic_load(f1p, __ATOMIC_RELAXED, __HIP_MEMORY_SCOPE_AGENT);
            ok = ok && (f1 >= tgt);
          }
        }
        if (__all(ok)) break;
        __builtin_amdgcn_s_sleep(1);
      }
      asm volatile("" ::: "memory");   // compiler fence: no data load crosses up
    }
    // ---- compute phase ----
    if (!IS1 || it >= 1){
      const int t = IS1 ? it-1 : it;
      bfrag8 ha[KF];
      if (IS1){
        const bf16* hb0 = h0seq + ((size_t)t*BB + (m0+lj))*HG;
        #pragma unroll
        for (int kf=0;kf<12;++kf) ha[kf] = ldfrag_coh(hb0 + kf*32 + lq*8);
        if (t > 0){
          const bf16* hb1 = h1seq + ((size_t)(m0+lj)*SS + (t-1))*HG;
          #pragma unroll
          for (int kf=12;kf<24;++kf) ha[kf] = ldfrag_coh(hb1 + (kf-12)*32 + lq*8);
        }
      } else if (t > 0){
        const bf16* hb = h0seq + ((size_t)(t-1)*BB + (m0+lj))*HG;
        #pragma unroll
        for (int kf=0;kf<12;++kf) ha[kf] = ldfrag_coh(hb + kf*32 + lq*8);
      }
      floatx4 aA0={0,0,0,0}, aB0={0,0,0,0}, aA1={0,0,0,0}, aB1={0,0,0,0};
      if (IS1 || t > 0){
        #pragma unroll
        for (int kf=0;kf<12;++kf){
          if (kf&1){ aB0 = MFMA16(ha[kf], asfrag(Wr0[kf]), aB0); aB1 = MFMA16(ha[kf], asfrag(Wr1[kf]), aB1); }
          else     { aA0 = MFMA16(ha[kf], asfrag(Wr0[kf]), aA0); aA1 = MFMA16(ha[kf], asfrag(Wr1[kf]), aA1); }
        }
      }
      if (IS1 && t > 0){
        #pragma unroll
        for (int kf=12;kf<24;++kf){
          if (kf&1){ aB0 = MFMA16(ha[kf], asfrag(Wr0[kf]), aB0); aB1 = MFMA16(ha[kf], asfrag(Wr1[kf]), aB1); }
          else     { aA0 = MFMA16(ha[kf], asfrag(Wr0[kf]), aA0); aA1 = MFMA16(ha[kf], asfrag(Wr1[kf]), aA1); }
        }
      }
      const floatx4 s0 = aA0 + aB0, s1 = aA1 + aB1;
      #pragma unroll
      for (int nt=0; nt<2; ++nt){
        #pragma unroll
        for (int r=0; r<4; ++r){
          float x = nt ? s1[r] : s0[r];
          x += IS1 ? (nt ? bi1 : bi0) : b2f(g0pre[nt][r]);
          float av = actv(x, isg);            // own gate only
          float i_ = __shfl(av, (l&60)|0);
          float f_ = __shfl(av, (l&60)|1);
          float g_ = __shfl(av, (l&60)|2);
          float o_ = __shfl(av, (l&60)|3);
          float cp = nt ? c1s[r] : c0s[r];
          float c = f_*cp + i_*g_;
          if (nt) c1s[r] = c; else c0s[r] = c;
          float h = o_*tanh_(c);
          float hn = __shfl(h, l^4);          // neighbor quad's h (a+1)
          if ((l&7) == 0){
            int bb = m0 + 4*lq + r;
            int jh = bl*8 + nt*4 + a;         // a even here
            bf16* hp = IS1 ? (h1seq + ((size_t)bb*SS + t)*HG + jh)
                           : (h0seq + ((size_t)t*BB + bb)*HG + jh);
            stpair_coh(hp, h, hn);
          }
        }
      }
    }
    // ---- signal phase: per-wave drain, then own-flag store ----
    asm volatile("s_waitcnt vmcnt(0)" ::: "memory");
    if (l == 0)
      __hip_atomic_store(myflag, (unsigned)(it+1),
                         __ATOMIC_RELAXED, __HIP_MEMORY_SCOPE_AGENT);
    // prefetch next round's G0 pre-acts (read-only, off the signal path)
    if (!IS1 && it+1 <= ITMAX){
      #pragma unroll
      for (int nt=0;nt<2;++nt)
        #pragma unroll
        for (int r=0;r<4;++r)
          g0pre[nt][r] = *(const unsigned short*)&G0t[((size_t)(it+1)*BB + m0 + 4*lq + r)*G4 + n0 + nt*16 + 4*a + gl];
    }
  }
}

__global__ __launch_bounds__(256,1) void graph_rnn(
    const bf16* __restrict__ G0t, const bf16* __restrict__ W0r, const bf16* __restrict__ W1c,
    const float* __restrict__ gb1, bf16* __restrict__ h0seq, bf16* __restrict__ h1seq,
    unsigned int* flags)
{
  if (blockIdx.x < 48) rnn_body<0>(blockIdx.x, threadIdx.x, G0t, W0r, gb1, h0seq, h1seq, flags);
  else                 rnn_body<1>(blockIdx.x, threadIdx.x, G0t, W1c, gb1, h0seq, h1seq, flags);
}

// ---------------------------------------------------------------------------
// fused 2-layer edge LSTM body (blocks 0..2047) + tag FFs (blocks 2048..2559)
// ---------------------------------------------------------------------------
__device__ void edge_body(int bid,
    const bf16* __restrict__ projb,
    const bf16* __restrict__ eW0b, const bf16* __restrict__ eW1ab, const bf16* __restrict__ eW1bb,
    const float* __restrict__ eb0, const float* __restrict__ eb1, const float* __restrict__ ew0c,
    const float* __restrict__ clsW, const float* __restrict__ clsb_p, const float* __restrict__ bos_p,
    const int* __restrict__ heads, float* __restrict__ arc)
{
  __shared__ alignas(16) bf16 hbuf0[16][72];
  __shared__ alignas(16) bf16 hbuf1[16][72];
  __shared__ float lbuf[4][16];
  const int tid = threadIdx.x, w = tid>>6, l = tid&63, lj = l&15, lq = l>>4;
  const int seq0 = bid * 16;
  const int jglob = w*16 + lj;
  for (int i = tid; i < 16*64; i += 256){
    int sl = i >> 6, jj = i & 63;
    bf16 v = projb[(size_t)(seq0+sl)*HE + jj];
    hbuf0[sl][jj] = v; hbuf1[sl][jj] = v;
  }
  bfrag8 W0f[4][2], W1af[4][2], W1bf[4][2];
  #pragma unroll
  for (int g=0; g<4; ++g){
    #pragma unroll
    for (int kk=0; kk<2; ++kk){
      size_t offw = (size_t)(g*HE + jglob)*HE + kk*32 + lq*8;
      W0f [g][kk] = *(const bfrag8*)&eW0b [offw];
      W1af[g][kk] = *(const bfrag8*)&eW1ab[offw];
      W1bf[g][kk] = *(const bfrag8*)&eW1bb[offw];
    }
  }
  float ebr0[4], ebr1[4], ewr[4];
  #pragma unroll
  for (int g=0; g<4; ++g){ ebr0[g]=eb0[g*HE+jglob]; ebr1[g]=eb1[g*HE+jglob]; ewr[g]=ew0c[g*HE+jglob]; }
  const float clswj = clsW[jglob];
  const float bos = bos_p[0], clsb = clsb_p[0];
  int hd[4]; float c0r[4]={0,0,0,0}, c1r[4]={0,0,0,0};
  #pragma unroll
  for (int r=0;r<4;++r){
    int sq = seq0 + 4*lq + r;
    int b = sq >> 9, s = sq & 511;
    hd[r] = (s==0) ? 0 : heads[b*TT + s - 1];
  }
  __syncthreads();
  for (int j=0; j<33; ++j){
    floatx4 acc0[4] = {};
    bfrag8 a0[2];
    #pragma unroll
    for (int kk=0; kk<2; ++kk)
      a0[kk] = *(const bfrag8*)((const char*)&hbuf0[0][0] + lj*144 + kk*64 + lq*16);
    #pragma unroll
    for (int g=0; g<4; ++g)
      #pragma unroll
      for (int kk=0; kk<2; ++kk)
        acc0[g] = MFMA16(a0[kk], W0f[g][kk], acc0[g]);
    __syncthreads();
    float h0v[4];
    #pragma unroll
    for (int r=0;r<4;++r){
      float x = (j==0) ? bos : ((hd[r] == j-1) ? 1.f : 0.f);
      float pi = acc0[0][r] + ebr0[0] + x*ewr[0];
      float pf = acc0[1][r] + ebr0[1] + x*ewr[1];
      float pg = acc0[2][r] + ebr0[2] + x*ewr[2];
      float po = acc0[3][r] + ebr0[3] + x*ewr[3];
      float i_=sigm_(pi), f_=sigm_(pf), g_=tanh_(pg), o_=sigm_(po);
      c0r[r] = f_*c0r[r] + i_*g_;
      h0v[r] = o_*tanh_(c0r[r]);
    }
    #pragma unroll
    for (int r=0;r<4;++r) hbuf0[4*lq + r][jglob] = __float2bfloat16(h0v[r]);
    __syncthreads();
    floatx4 acc1[4] = {};
    bfrag8 a1[2], a2[2];
    #pragma unroll
    for (int kk=0;kk<2;++kk){
      a1[kk] = *(const bfrag8*)((const char*)&hbuf0[0][0] + lj*144 + kk*64 + lq*16);
      a2[kk] = *(const bfrag8*)((const char*)&hbuf1[0][0] + lj*144 + kk*64 + lq*16);
    }
    #pragma unroll
    for (int g=0; g<4; ++g){
      #pragma unroll
      for (int kk=0;kk<2;++kk){
        acc1[g] = MFMA16(a1[kk], W1af[g][kk], acc1[g]);
        acc1[g] = MFMA16(a2[kk], W1bf[g][kk], acc1[g]);
      }
    }
    __syncthreads();
    float p[4];
    #pragma unroll
    for (int r=0;r<4;++r){
      float pi = acc1[0][r] + ebr1[0];
      float pf = acc1[1][r] + ebr1[1];
      float pg = acc1[2][r] + ebr1[2];
      float po = acc1[3][r] + ebr1[3];
      float i_=sigm_(pi), f_=sigm_(pf), g_=tanh_(pg), o_=sigm_(po);
      c1r[r] = f_*c1r[r] + i_*g_;
      float h1 = o_*tanh_(c1r[r]);
      hbuf1[4*lq + r][jglob] = __float2bfloat16(h1);
      p[r] = h1 * clswj;
    }
    #pragma unroll
    for (int mk=1; mk<16; mk<<=1)
      #pragma unroll
      for (int r=0;r<4;++r) p[r] += __shfl_xor(p[r], mk, 64);
    if (lj == 0){
      #pragma unroll
      for (int r=0;r<4;++r) lbuf[w][4*lq + r] = p[r];
    }
    __syncthreads();
    if (tid < 16 && j >= 1){
      int sq = seq0 + tid;
      float v = lbuf[0][tid] + lbuf[1][tid] + lbuf[2][tid] + lbuf[3][tid] + clsb;
      arc[(size_t)sq*SS + (j-1)] = v;
    }
  }
}

__global__ __launch_bounds__(256) void edge_tag(
    const bf16* __restrict__ projb,
    const bf16* __restrict__ eW0b, const bf16* __restrict__ eW1ab, const bf16* __restrict__ eW1bb,
    const float* __restrict__ eb0, const float* __restrict__ eb1, const float* __restrict__ ew0c,
    const float* __restrict__ clsW, const float* __restrict__ clsb_p, const float* __restrict__ bos_p,
    const int* __restrict__ heads, float* __restrict__ arc,
    const bf16* __restrict__ h1seq,
    const bf16* __restrict__ htWb, const float* __restrict__ htb,
    const bf16* __restrict__ dtWb, const float* __restrict__ dtb,
    const int* __restrict__ mask, float* __restrict__ out_ht, float* __restrict__ out_dt)
{
  const int b = blockIdx.x;
  if (b < 2048)      edge_body(b, projb, eW0b, eW1ab, eW1bb, eb0, eb1, ew0c,
                               clsW, clsb_p, bos_p, heads, arc);
  else if (b < 2304) gemm_body<HG,128,2,2,2>(b-2048, h1seq, htWb, htb, mask, (void*)out_ht, 100);
  else               gemm_body<HG,128,2,2,2>(b-2304, h1seq, dtWb, dtb, mask, (void*)out_dt, 100);
}

// ---------------------------------------------------------------------------
extern "C" void kernel_launch(void* const* d_in, const int* in_sizes, int n_in,
                              void* d_out, int out_size, void* d_ws, size_t ws_size,
                              hipStream_t stream)
{
  const float* input = (const float*)d_in[0];
  const float* tag   = (const float*)d_in[1];
  const int*   mask  = (const int*)  d_in[2];
  const int*   heads = (const int*)  d_in[3];
  const float* sent  = (const float*)d_in[4];
  const float* bosp  = (const float*)d_in[5];
  const float* gWih0 = (const float*)d_in[6];
  const float* gWhh0 = (const float*)d_in[7];
  const float* gbih0 = (const float*)d_in[8];
  const float* gbhh0 = (const float*)d_in[9];
  const float* gWih1 = (const float*)d_in[10];
  const float* gWhh1 = (const float*)d_in[11];
  const float* gbih1 = (const float*)d_in[12];
  const float* gbhh1 = (const float*)d_in[13];
  const float* eWih0 = (const float*)d_in[14];
  const float* eWhh0 = (const float*)d_in[15];
  const float* ebih0 = (const float*)d_in[16];
  const float* ebhh0 = (const float*)d_in[17];
  const float* eWih1 = (const float*)d_in[18];
  const float* eWhh1 = (const float*)d_in[19];
  const float* ebih1 = (const float*)d_in[20];
  const float* ebhh1 = (const float*)d_in[21];
  const float* g2eW  = (const float*)d_in[22];
  const float* g2eb  = (const float*)d_in[23];
  const float* clsW  = (const float*)d_in[24];
  const float* clsb  = (const float*)d_in[25];
  const float* htW   = (const float*)d_in[26];
  const float* htb   = (const float*)d_in[27];
  const float* dtW   = (const float*)d_in[28];
  const float* dtb   = (const float*)d_in[29];

  char* wsb = (char*)d_ws;
  size_t off = 0;
  auto take = [&](size_t bytes)->char* {
    char* p = wsb + off;
    off = (off + bytes + 255) & ~(size_t)255;
    return p;
  };
  bf16*  Xb     = (bf16*) take((size_t)NSEQ*KXP*2);   // 33.6 MB
  bf16*  W0i    = (bf16*) take((size_t)G4*KXP*2);     // interleaved Wih0
  bf16*  W0r    = (bf16*) take((size_t)G4*HG*2);      // interleaved Whh0
  bf16*  W1c    = (bf16*) take((size_t)G4*768*2);     // interleaved [Wih1|Whh1]
  float* gb0i   = (float*)take(G4*4);
  float* gb1i   = (float*)take(G4*4);
  bf16*  G0t    = (bf16*) take((size_t)NSEQ*G4*2);    // 100.7 MB, time-major [t][b][1536]
  bf16*  h0seq  = (bf16*) take((size_t)SS*BB*HG*2);   // 25.2 MB [t][b][384], write-once
  bf16*  h1seq  = (bf16*) take((size_t)NSEQ*HG*2);    // 25.2 MB [b][t][384], write-once
  unsigned int* flags = (unsigned int*)take(384*16*4);// 384 per-wave flag lines (64B each)
  bf16*  projb  = (bf16*) take((size_t)NSEQ*HE*2);
  bf16*  eW0b   = (bf16*) take(E4*HE*2);
  bf16*  eW1ab  = (bf16*) take(E4*HE*2);
  bf16*  eW1bb  = (bf16*) take(E4*HE*2);
  float* eb0w   = (float*)take(E4*4);
  float* eb1w   = (float*)take(E4*4);
  float* ew0cw  = (float*)take(E4*4);
  bf16*  g2eWb  = (bf16*) take(HE*HG*2);
  bf16*  htWb   = (bf16*) take(128*HG*2);
  bf16*  dtWb   = (bf16*) take(128*HG*2);

  (void)hipMemsetAsync(d_out, 0, (size_t)16777216*4, stream);
  (void)hipMemsetAsync(flags, 0, 384*16*4, stream);

  prep_x<<<2048,256,0,stream>>>(input, tag, sent, Xb);
  prep_w<<<512,256,0,stream>>>(gWih0,gWhh0,gbih0,gbhh0,gWih1,gWhh1,gbih1,gbhh1,
                               eWih0,eWhh0,ebih0,ebhh0,eWih1,eWhh1,ebih1,ebhh1,
                               g2eW,htW,dtW,
                               W0i,W0r,W1c,gb0i,gb1i,eW0b,eW1ab,eW1bb,
                               eb0w,eb1w,ew0cw,g2eWb,htWb,dtWb);

  // layer-0 input gates, time-major (plain coalesced stores)
  gemm_g0<<<3072,256,0,stream>>>(Xb, W0i, gb0i, G0t);

  // persistent 2-layer recurrence — per-wave flags, write-once h buffers
  graph_rnn<<<96,256,0,stream>>>(G0t, W0r, W1c, gb1i, h0seq, h1seq, flags);

  // proj (must precede edge_tag)
  gemm_proj<<<256,256,0,stream>>>(h1seq, g2eWb, g2eb, mask, projb);

  // edge LSTM + both tag FFs fused (tags overlap the edge recurrence)
  edge_tag<<<2560,256,0,stream>>>(projb, eW0b, eW1ab, eW1bb, eb0w, eb1w, ew0cw,
                                  clsW, clsb, bosp, heads, (float*)d_out,
                                  h1seq, htWb, htb, dtWb, dtb, mask,
                                  (float*)d_out + 16777216,
                                  (float*)d_out + 16777216 + 3276800);
}